// Round 19
// baseline (88.825 us; speedup 1.0000x reference)
//
#include <hip/hip_runtime.h>
#include <hip/hip_fp16.h>
#include <math.h>

#define TT 16
#define HH 64
#define WW 64
#define CC 128
#define PI2 6.283185307179586f

// XOR digit swizzle: row r = hi*8+lo -> hi*8 + (lo^hi). Keeps stride-8 and
// block-8 row accesses <=2-way banked in the narrow [.,64][4] tiles.
#define LROW(r) (((r) & 0x38) | ((((r) >> 3) ^ (r)) & 7))

__device__ __forceinline__ float2 cadd(float2 a, float2 b){ return make_float2(a.x+b.x, a.y+b.y); }
__device__ __forceinline__ float2 csub(float2 a, float2 b){ return make_float2(a.x-b.x, a.y-b.y); }
__device__ __forceinline__ float2 cmul(float2 a, float2 b) {
    return make_float2(a.x*b.x - a.y*b.y, a.x*b.y + a.y*b.x);
}
__device__ __forceinline__ float2 cmac(float2 acc, float2 a, float2 b) {
    acc.x = fmaf(a.x, b.x, fmaf(-a.y, b.y, acc.x));
    acc.y = fmaf(a.x, b.y, fmaf(a.y, b.x, acc.y));
    return acc;
}
__device__ __forceinline__ float2 csq(float2 a) {
    return make_float2(a.x*a.x - a.y*a.y, 2.f*a.x*a.y);
}

// ---------------- radix butterflies ----------------
template<int SGN>
__device__ __forceinline__ void dft4(float2 b0, float2 b1, float2 b2, float2 b3,
                                     float2& y0, float2& y1, float2& y2, float2& y3) {
    float2 e0 = cadd(b0, b2), e1 = csub(b0, b2);
    float2 o0 = cadd(b1, b3), o1 = csub(b1, b3);
    y0 = cadd(e0, o0); y2 = csub(e0, o0);
    float2 r = make_float2((float)(-SGN) * o1.y, (float)SGN * o1.x);
    y1 = cadd(e1, r); y3 = csub(e1, r);
}

template<int SGN>
__device__ __forceinline__ void dft8(const float2* a, float2* X) {
    const float C = 0.70710678118654752f;
    float2 E0,E1,E2,E3,O0,O1,O2,O3;
    dft4<SGN>(a[0],a[2],a[4],a[6], E0,E1,E2,E3);
    dft4<SGN>(a[1],a[3],a[5],a[7], O0,O1,O2,O3);
    float2 T1 = make_float2(C*(O1.x - (float)SGN*O1.y), C*((float)SGN*O1.x + O1.y));
    float2 T2 = make_float2((float)(-SGN)*O2.y, (float)SGN*O2.x);
    float2 T3 = make_float2(-C*(O3.x + (float)SGN*O3.y), C*((float)SGN*O3.x - O3.y));
    X[0]=cadd(E0,O0); X[4]=csub(E0,O0);
    X[1]=cadd(E1,T1); X[5]=csub(E1,T1);
    X[2]=cadd(E2,T2); X[6]=csub(E2,T2);
    X[3]=cadd(E3,T3); X[7]=csub(E3,T3);
}

template<int SGN>
__device__ __forceinline__ void dft16(const float2* v, float2* X) {
    const float ct[10] = {1.f, 0.92387953251f, 0.70710678119f, 0.38268343236f, 0.f,
                          0.f, -0.70710678119f, 0.f, 0.f, -0.92387953251f};
    const float st[10] = {0.f, 0.38268343236f, 0.70710678119f, 0.92387953251f, 1.f,
                          0.f, 0.70710678119f, 0.f, 0.f, -0.38268343236f};
    float2 Z[16];
    #pragma unroll
    for (int h0 = 0; h0 < 4; ++h0) {
        float2 y0,y1,y2,y3;
        dft4<SGN>(v[h0], v[4+h0], v[8+h0], v[12+h0], y0,y1,y2,y3);
        float2 ys[4] = {y0,y1,y2,y3};
        #pragma unroll
        for (int k0 = 0; k0 < 4; ++k0) {
            int m = h0 * k0;
            float cc = ct[m], ss = (float)SGN * st[m];
            Z[k0*4 + h0] = make_float2(ys[k0].x*cc - ys[k0].y*ss,
                                       ys[k0].x*ss + ys[k0].y*cc);
        }
    }
    #pragma unroll
    for (int k0 = 0; k0 < 4; ++k0) {
        float2 y0,y1,y2,y3;
        dft4<SGN>(Z[k0*4+0], Z[k0*4+1], Z[k0*4+2], Z[k0*4+3], y0,y1,y2,y3);
        X[k0] = y0; X[k0+4] = y1; X[k0+8] = y2; X[k0+12] = y3;
    }
}

// Z layout (uint4 = 4 half2 = 4 channels): index ((om*32 + cc)*16 + t)*64 + h.
// G table (half2): Ghw[((om*64 + ep)*128 + c)*16 + ta]  -- 64 B per (ep,om,c), ta-contig.

// ======== fused pass A: blocks 0..1023 = p1 (paired real W-FFT), 1024..1155 = G-prep ====
__global__ __launch_bounds__(256) void pA(const float* __restrict__ x,
                                          uint4* __restrict__ Z,
                                          const float* __restrict__ Ak,
                                          const float* __restrict__ Bk,
                                          __half2* __restrict__ Ghw) {
    __shared__ __align__(16) char smem[36352];
    int bid = blockIdx.x;
    int tid = threadIdx.x;
    if (bid < 1024) {
        // ---- p1 role (r17-verified): fp32 SoA LDS, half2 only at Z write ----
        float (*zsre)[64][32] = (float(*)[64][32])smem;             // 16 KB
        float (*zsim)[64][32] = (float(*)[64][32])(smem + 16384);   // 16 KB
        float (*spre)[64][32] = (float(*)[64][32])smem;             // alias
        float (*spim)[64][32] = (float(*)[64][32])(smem + 16384);   // alias
        int cq = bid & 3, hq = (bid >> 2) & 15, t = bid >> 6;
        int c = tid & 31, s4 = tid >> 5;           // s4 in [0,8)
        float twc[8], tws[8];
        {
            float s1, c1; sincosf(-PI2 * s4 / 64.0f, &s1, &c1);
            twc[0] = 1.f; tws[0] = 0.f;
            #pragma unroll
            for (int k = 1; k < 8; ++k) {
                twc[k] = twc[k-1]*c1 - tws[k-1]*s1;
                tws[k] = twc[k-1]*s1 + tws[k-1]*c1;
            }
        }
        const float* xb = x + (size_t)(t*64 + hq*4) * 8192 + cq * 32 + c;
        #pragma unroll
        for (int p = 0; p < 2; ++p) {
            float2 a[8], Y[8];
            #pragma unroll
            for (int h1 = 0; h1 < 8; ++h1) {
                size_t off = (size_t)(h1*8 + s4) * 128;
                a[h1] = make_float2(xb[(size_t)(2*p) * 8192 + off],
                                    xb[(size_t)(2*p+1) * 8192 + off]);
            }
            dft8<-1>(a, Y);
            #pragma unroll
            for (int k0 = 0; k0 < 8; ++k0) {
                int row = k0*8 + s4;
                zsre[p][row][c] = Y[k0].x*twc[k0] - Y[k0].y*tws[k0];
                zsim[p][row][c] = Y[k0].x*tws[k0] + Y[k0].y*twc[k0];
            }
        }
        __syncthreads();                                      // B1
        float2 X0[8], X1[8];
        {
            float2 b[8];
            #pragma unroll
            for (int h0 = 0; h0 < 8; ++h0)
                b[h0] = make_float2(zsre[0][s4*8 + h0][c], zsim[0][s4*8 + h0][c]);
            dft8<-1>(b, X0);
            #pragma unroll
            for (int h0 = 0; h0 < 8; ++h0)
                b[h0] = make_float2(zsre[1][s4*8 + h0][c], zsim[1][s4*8 + h0][c]);
            dft8<-1>(b, X1);
        }
        __syncthreads();                                      // B2 (alias safe)
        #pragma unroll
        for (int k1 = 0; k1 < 8; ++k1) {
            int row = s4 + 8*k1;
            spre[0][row][c] = X0[k1].x; spim[0][row][c] = X0[k1].y;
            spre[1][row][c] = X1[k1].x; spim[1][row][c] = X1[k1].y;
        }
        __syncthreads();                                      // B3
        for (int i = tid; i < 528; i += 256) {                // p(2) x ccl(8) x om(33)
            int p = i & 1, ccl = (i >> 1) & 7, om = i >> 4;
            int mo = (64 - om) & 63;
            uint4 u1, u2;
            unsigned int* p1o = &u1.x;
            unsigned int* p2o = &u2.x;
            #pragma unroll
            for (int j = 0; j < 4; ++j) {
                int cb = ccl*4 + j;
                float2 za = make_float2(spre[p][om][cb], spim[p][om][cb]);
                float2 zb = make_float2(spre[p][mo][cb], spim[p][mo][cb]);
                float2 Xa = make_float2(0.5f*(za.x + zb.x), 0.5f*(za.y - zb.y));
                float2 Xb = make_float2(0.5f*(za.y + zb.y), 0.5f*(zb.x - za.x));
                __half2 h1v = __float22half2_rn(Xa);
                __half2 h2v = __float22half2_rn(Xb);
                p1o[j] = *(unsigned int*)&h1v;
                p2o[j] = *(unsigned int*)&h2v;
            }
            size_t base = ((size_t)(om*32 + cq*8 + ccl)*16 + t)*64 + hq*4;
            Z[base + 2*p]     = u1;
            Z[base + 2*p + 1] = u2;
        }
    } else {
        // ---- G-prep role: tanh + kw/kh DFTs + full G(ta) = S(A_f)B_f table ----
        // LDS: Asl@0 (12544), Bsl@12544 (12544), Awl@25088 half2[3][7][64] (5376),
        //      Bwl@30464 (5376), tw64@35840 (512)  -> 36352 B
        float (*Asl)[7][64]   = (float(*)[7][64])smem;
        float (*Bsl)[7][64]   = (float(*)[7][64])(smem + 12544);
        __half2 (*Awl)[7][64] = (__half2(*)[7][64])(smem + 25088);
        __half2 (*Bwl)[7][64] = (__half2(*)[7][64])(smem + 30464);
        float2* tw64          = (float2*)(smem + 35840);
        int kid = bid - 1024;                       // [0,132)
        int eh = kid & 1, chalf = (kid >> 1) & 1, om = kid >> 2;   // om in [0,33)
        int c0 = chalf * 64;
        for (int i = tid; i < 64; i += 256) {
            float s, cw; sincosf(-PI2 * i / 64.0f, &s, &cw);
            tw64[i] = make_float2(cw, s);
        }
        __syncthreads();
        for (int kt = 0; kt < 3; ++kt) {
            for (int i = tid; i < 49 * 64; i += 256) {
                int p = i >> 6, cl = i & 63;
                int kh = p / 7, kw = p % 7;
                int idx = (((c0 + cl) * 3 + kt) * 7 + kh) * 7 + kw;
                Asl[kh][kw][cl] = 0.9f * tanhf(Ak[idx]);
                Bsl[kh][kw][cl] = Bk[idx];
            }
            __syncthreads();
            for (int i = tid; i < 7 * 64; i += 256) {
                int kh = i >> 6, cl = i & 63;
                float2 aA = make_float2(0.f,0.f), aB = make_float2(0.f,0.f);
                #pragma unroll
                for (int kw = 0; kw < 7; ++kw) {
                    float2 tw = tw64[(om * (kw - 3)) & 63];
                    float va = Asl[kh][kw][cl], vb = Bsl[kh][kw][cl];
                    aA.x = fmaf(va, tw.x, aA.x); aA.y = fmaf(va, tw.y, aA.y);
                    aB.x = fmaf(vb, tw.x, aB.x); aB.y = fmaf(vb, tw.y, aB.y);
                }
                Awl[kt][kh][cl] = __float22half2_rn(aA);
                Bwl[kt][kh][cl] = __float22half2_rn(aB);
            }
            __syncthreads();
        }
        // per (eta, cl): kh-DFT for 3 kt, then 16-ta G chain
        const float CT16[16] = {1.f, 0.9238795325f, 0.7071067812f, 0.3826834324f, 0.f,
                                -0.3826834324f, -0.7071067812f, -0.9238795325f, -1.f,
                                -0.9238795325f, -0.7071067812f, -0.3826834324f, 0.f,
                                0.3826834324f, 0.7071067812f, 0.9238795325f};
        const float ST16[16] = {0.f, 0.3826834324f, 0.7071067812f, 0.9238795325f, 1.f,
                                0.9238795325f, 0.7071067812f, 0.3826834324f, 0.f,
                                -0.3826834324f, -0.7071067812f, -0.9238795325f, -1.f,
                                -0.9238795325f, -0.7071067812f, -0.3826834324f};
        for (int i = tid; i < 32 * 64; i += 256) {
            int eta = eh * 32 + (i >> 6), cl = i & 63;
            float2 A0 = make_float2(0.f,0.f), A1 = A0, A2 = A0;
            float2 B0 = A0, B1 = A0, B2 = A0;
            #pragma unroll
            for (int kh = 0; kh < 7; ++kh) {
                float2 tw = tw64[(eta * (kh - 3)) & 63];
                A0 = cmac(A0, __half22float2(Awl[0][kh][cl]), tw);
                A1 = cmac(A1, __half22float2(Awl[1][kh][cl]), tw);
                A2 = cmac(A2, __half22float2(Awl[2][kh][cl]), tw);
                B0 = cmac(B0, __half22float2(Bwl[0][kh][cl]), tw);
                B1 = cmac(B1, __half22float2(Bwl[1][kh][cl]), tw);
                B2 = cmac(B2, __half22float2(Bwl[2][kh][cl]), tw);
            }
            int ep = ((eta & 7) << 3) | (eta >> 3);  // digit-swapped eta position
            size_t gb = ((size_t)(om*64 + ep)*128 + c0 + cl) * 16;
            #pragma unroll
            for (int ta = 0; ta < 16; ++ta) {
                float2 wv = make_float2(CT16[ta], -ST16[ta]);
                float2 wc = make_float2(CT16[ta],  ST16[ta]);
                float2 Af = A1; Af = cmac(Af, A0, wc); Af = cmac(Af, A2, wv);
                float2 Bf = B1; Bf = cmac(Bf, B0, wc); Bf = cmac(Bf, B2, wv);
                float2 A2q = csq(Af), A4q = csq(A2q);
                float2 S = cmul(make_float2(1.f+Af.x, Af.y), make_float2(1.f+A2q.x, A2q.y));
                S = cmul(S, make_float2(1.f+A4q.x, A4q.y));
                float2 G = cmul(S, Bf);
                Ghw[gb + ta] = __float22half2_rn(G);
            }
        }
    }
}

// ------- fused middle pass: fp32 SoA LDS; T-phase = dft16 + 16 G-mults + dft16 -------
__global__ __launch_bounds__(256) void pmid(uint4* __restrict__ Z,
                                            const __half2* __restrict__ Ghw) {
    __shared__ float tre[16][64][4];      // 16 KB
    __shared__ float tim[16][64][4];      // 16 KB
    int l = (blockIdx.x & 7) * 132 + (blockIdx.x >> 3);   // XCD-chunked, bijective
    int om = l >> 5, cc = l & 31;
    int c0 = cc * 4;
    int tid = threadIdx.x;
    uint4* g = Z + (size_t)l * 1024;

    // prefetch this thread's 16 G values (4 consecutive uint4, issued early)
    int cg = tid & 3, rT = tid >> 2;                 // rT in [0,64)
    const uint4* Gp = (const uint4*)(Ghw + ((size_t)(om*64 + rT)*128 + c0 + cg)*16);
    uint4 gq0 = Gp[0], gq1 = Gp[1], gq2 = Gp[2], gq3 = Gp[3];

    int d = tid & 7;
    float twc[8], tws[8];
    {
        float s1, c1; sincosf(-PI2 * d / 64.0f, &s1, &c1);
        twc[0] = 1.f; tws[0] = 0.f;
        #pragma unroll
        for (int k = 1; k < 8; ++k) {
            twc[k] = twc[k-1]*c1 - tws[k-1]*s1;
            tws[k] = twc[k-1]*s1 + tws[k-1]*c1;
        }
    }
    for (int i = tid; i < 1024; i += 256) {
        uint4 u = g[i];
        int t = i >> 6, h = i & 63;
        int pr = LROW(h);
        float2 v0 = __half22float2(*(__half2*)&u.x);
        float2 v1 = __half22float2(*(__half2*)&u.y);
        float2 v2 = __half22float2(*(__half2*)&u.z);
        float2 v3 = __half22float2(*(__half2*)&u.w);
        tre[t][pr][0] = v0.x; tim[t][pr][0] = v0.y;
        tre[t][pr][1] = v1.x; tim[t][pr][1] = v1.y;
        tre[t][pr][2] = v2.x; tim[t][pr][2] = v2.y;
        tre[t][pr][3] = v3.x; tim[t][pr][3] = v3.y;
    }
    __syncthreads();
    int cl = (tid >> 3) & 3, ts = tid >> 5;          // ts in [0,8)
    // H forward stage 1
    #pragma unroll
    for (int q = 0; q < 2; ++q) {
        int t = ts*2 + q;
        float2 a[8], Y[8];
        #pragma unroll
        for (int h1 = 0; h1 < 8; ++h1) {
            int pr = LROW(h1*8 + d);
            a[h1] = make_float2(tre[t][pr][cl], tim[t][pr][cl]);
        }
        dft8<-1>(a, Y);
        #pragma unroll
        for (int k0 = 0; k0 < 8; ++k0) {
            int pr = LROW(k0*8 + d);
            tre[t][pr][cl] = Y[k0].x*twc[k0] - Y[k0].y*tws[k0];
            tim[t][pr][cl] = Y[k0].x*tws[k0] + Y[k0].y*twc[k0];
        }
    }
    __syncthreads();
    // H forward stage 2
    #pragma unroll
    for (int q = 0; q < 2; ++q) {
        int t = ts*2 + q;
        float2 a[8], Y[8];
        #pragma unroll
        for (int h0 = 0; h0 < 8; ++h0) {
            int pr = LROW(d*8 + h0);
            a[h0] = make_float2(tre[t][pr][cl], tim[t][pr][cl]);
        }
        dft8<-1>(a, Y);
        #pragma unroll
        for (int k1 = 0; k1 < 8; ++k1) {
            int pr = LROW(d*8 + k1);
            tre[t][pr][cl] = Y[k1].x; tim[t][pr][cl] = Y[k1].y;
        }
    }
    __syncthreads();
    // T phase: dft16 -> 16 G mults (precomputed) -> inv dft16
    {
        int pr = LROW(rT);
        float2 v[16], X[16];
        #pragma unroll
        for (int t = 0; t < 16; ++t) v[t] = make_float2(tre[t][pr][cg], tim[t][pr][cg]);
        dft16<-1>(v, X);
        const unsigned int* gw = &gq0.x;   // gq0..gq3 are contiguous? use per-quad unpack
        unsigned int gwa[16] = {gq0.x, gq0.y, gq0.z, gq0.w,
                                gq1.x, gq1.y, gq1.z, gq1.w,
                                gq2.x, gq2.y, gq2.z, gq2.w,
                                gq3.x, gq3.y, gq3.z, gq3.w};
        (void)gw;
        #pragma unroll
        for (int ta = 0; ta < 16; ++ta) {
            float2 G = __half22float2(*(const __half2*)&gwa[ta]);
            X[ta] = cmul(X[ta], G);
        }
        dft16<1>(X, v);
        const float sc = 0.015625f;                  // 1/64 fold
        #pragma unroll
        for (int t = 0; t < 16; ++t) {
            tre[t][pr][cg] = v[t].x * sc;
            tim[t][pr][cg] = v[t].y * sc;
        }
    }
    __syncthreads();
    // inverse H stage 1
    #pragma unroll
    for (int q = 0; q < 2; ++q) {
        int t = ts*2 + q;
        float2 a[8], Y[8];
        #pragma unroll
        for (int e1 = 0; e1 < 8; ++e1) {
            int pr = LROW(d*8 + e1);
            a[e1] = make_float2(tre[t][pr][cl], tim[t][pr][cl]);
        }
        dft8<1>(a, Y);
        #pragma unroll
        for (int h0 = 0; h0 < 8; ++h0) {
            int pr = LROW(d*8 + h0);
            tre[t][pr][cl] =  Y[h0].x*twc[h0] + Y[h0].y*tws[h0];
            tim[t][pr][cl] = -Y[h0].x*tws[h0] + Y[h0].y*twc[h0];
        }
    }
    __syncthreads();
    // inverse H stage 2
    #pragma unroll
    for (int q = 0; q < 2; ++q) {
        int t = ts*2 + q;
        float2 a[8], Y[8];
        #pragma unroll
        for (int e0 = 0; e0 < 8; ++e0) {
            int pr = LROW(e0*8 + d);
            a[e0] = make_float2(tre[t][pr][cl], tim[t][pr][cl]);
        }
        dft8<1>(a, Y);
        #pragma unroll
        for (int h1 = 0; h1 < 8; ++h1) {
            int pr = LROW(d + 8*h1);
            tre[t][pr][cl] = Y[h1].x; tim[t][pr][cl] = Y[h1].y;
        }
    }
    __syncthreads();
    for (int i = tid; i < 1024; i += 256) {
        int t = i >> 6, h = i & 63;
        int pr = LROW(h);
        uint4 u;
        __half2 v0 = __float22half2_rn(make_float2(tre[t][pr][0], tim[t][pr][0]));
        __half2 v1 = __float22half2_rn(make_float2(tre[t][pr][1], tim[t][pr][1]));
        __half2 v2 = __float22half2_rn(make_float2(tre[t][pr][2], tim[t][pr][2]));
        __half2 v3 = __float22half2_rn(make_float2(tre[t][pr][3], tim[t][pr][3]));
        u.x = *(unsigned int*)&v0; u.y = *(unsigned int*)&v1;
        u.z = *(unsigned int*)&v2; u.w = *(unsigned int*)&v3;
        g[i] = u;
    }
}

// ------- pass 5 (r17-verified): paired inverse real-output W-FFT, fp32 SoA LDS -------
__global__ __launch_bounds__(256) void p5(const uint4* __restrict__ Z,
                                          float* __restrict__ out) {
    __shared__ float plre[2][64][32];      // 16 KB
    __shared__ float plim[2][64][32];      // 16 KB
    __shared__ float2 tw64[64];
    int bid = blockIdx.x;
    int cq = bid & 3, hq = (bid >> 2) & 15, t = bid >> 6;
    int tid = threadIdx.x;
    if (tid < 64) {
        float s, cw; sincosf(PI2 * tid / 64.0f, &s, &cw);
        tw64[tid] = make_float2(cw, s);
    }
    for (int i = tid; i < 528; i += 256) {               // p(2) x ccl(8) x om(33)
        int p = i & 1, ccl = (i >> 1) & 7, om = i >> 4;
        size_t base = ((size_t)(om*32 + cq*8 + ccl)*16 + t)*64 + hq*4;
        uint4 ua = Z[base + 2*p];
        uint4 ub = Z[base + 2*p + 1];
        const unsigned int* pa = &ua.x;
        const unsigned int* pb = &ub.x;
        #pragma unroll
        for (int j = 0; j < 4; ++j) {
            float2 za = __half22float2(*(const __half2*)&pa[j]);
            float2 zb = __half22float2(*(const __half2*)&pb[j]);
            plre[p][om][ccl*4+j] = za.x - zb.y;
            plim[p][om][ccl*4+j] = za.y + zb.x;
            if (om >= 1 && om <= 31) {
                plre[p][64-om][ccl*4+j] = za.x + zb.y;
                plim[p][64-om][ccl*4+j] = zb.x - za.y;
            }
        }
    }
    __syncthreads();                                          // B1
    int c = tid & 31, s4 = tid >> 5;
    float2 ar[2][8];
    #pragma unroll
    for (int p = 0; p < 2; ++p)
        #pragma unroll
        for (int h1 = 0; h1 < 8; ++h1)
            ar[p][h1] = make_float2(plre[p][h1*8 + s4][c], plim[p][h1*8 + s4][c]);
    __syncthreads();                                          // B2
    #pragma unroll
    for (int p = 0; p < 2; ++p) {
        float2 Y[8];
        dft8<1>(ar[p], Y);
        #pragma unroll
        for (int k0 = 0; k0 < 8; ++k0) {
            float2 z = cmul(Y[k0], tw64[(s4 * k0) & 63]);
            plre[p][k0*8 + s4][c] = z.x;
            plim[p][k0*8 + s4][c] = z.y;
        }
    }
    __syncthreads();                                          // B3
    #pragma unroll
    for (int p = 0; p < 2; ++p) {
        float2 b[8], X[8];
        #pragma unroll
        for (int h0 = 0; h0 < 8; ++h0)
            b[h0] = make_float2(plre[p][s4*8 + h0][c], plim[p][s4*8 + h0][c]);
        dft8<1>(b, X);
        float* dst = out + (size_t)(t*64 + hq*4 + 2*p) * 8192 + cq * 32 + c;
        #pragma unroll
        for (int k1 = 0; k1 < 8; ++k1) {
            size_t o = (size_t)(s4 + 8*k1) * 128;
            dst[o]        = X[k1].x * (1.0f / 1024.0f);
            dst[o + 8192] = X[k1].y * (1.0f / 1024.0f);
        }
    }
}

extern "C" void kernel_launch(void* const* d_in, const int* in_sizes, int n_in,
                              void* d_out, int out_size, void* d_ws, size_t ws_size,
                              hipStream_t stream) {
    const float* x  = (const float*)d_in[0];
    const float* Ak = (const float*)d_in[1];
    const float* Bk = (const float*)d_in[2];
    float* out = (float*)d_out;

    // Z: 33*32 chunks x 16 KB = 17.3 MB; G table: 33*64*128*16 half2 = 17.3 MB.
    uint4* Z = (uint4*)d_ws;
    __half2* Ghw = (__half2*)((char*)d_ws + (size_t)33*32*1024*16);

    hipLaunchKernelGGL(pA,   dim3(1156), dim3(256), 0, stream, x, Z, Ak, Bk, Ghw);
    hipLaunchKernelGGL(pmid, dim3(1056), dim3(256), 0, stream, Z, Ghw);
    hipLaunchKernelGGL(p5,   dim3(1024), dim3(256), 0, stream, Z, out);
}

// Round 20
// 56.815 us; speedup vs baseline: 1.5634x; 1.5634x over previous
//
#include <hip/hip_runtime.h>
#include <hip/hip_fp16.h>
#include <math.h>

#define TT 16
#define HH 64
#define WW 64
#define CC 128
#define PI2 6.283185307179586f

// XOR digit swizzle: row r = hi*8+lo -> hi*8 + (lo^hi). Keeps stride-8 and
// block-8 row accesses <=2-way banked in the narrow [.,64][4] tiles.
#define LROW(r) (((r) & 0x38) | ((((r) >> 3) ^ (r)) & 7))

__device__ __forceinline__ float2 cadd(float2 a, float2 b){ return make_float2(a.x+b.x, a.y+b.y); }
__device__ __forceinline__ float2 csub(float2 a, float2 b){ return make_float2(a.x-b.x, a.y-b.y); }
__device__ __forceinline__ float2 cmul(float2 a, float2 b) {
    return make_float2(a.x*b.x - a.y*b.y, a.x*b.y + a.y*b.x);
}
__device__ __forceinline__ float2 cmac(float2 acc, float2 a, float2 b) {
    acc.x = fmaf(a.x, b.x, fmaf(-a.y, b.y, acc.x));
    acc.y = fmaf(a.x, b.y, fmaf(a.y, b.x, acc.y));
    return acc;
}
__device__ __forceinline__ float2 csq(float2 a) {
    return make_float2(a.x*a.x - a.y*a.y, 2.f*a.x*a.y);
}

// ---------------- radix butterflies ----------------
template<int SGN>
__device__ __forceinline__ void dft4(float2 b0, float2 b1, float2 b2, float2 b3,
                                     float2& y0, float2& y1, float2& y2, float2& y3) {
    float2 e0 = cadd(b0, b2), e1 = csub(b0, b2);
    float2 o0 = cadd(b1, b3), o1 = csub(b1, b3);
    y0 = cadd(e0, o0); y2 = csub(e0, o0);
    float2 r = make_float2((float)(-SGN) * o1.y, (float)SGN * o1.x);
    y1 = cadd(e1, r); y3 = csub(e1, r);
}

template<int SGN>
__device__ __forceinline__ void dft8(const float2* a, float2* X) {
    const float C = 0.70710678118654752f;
    float2 E0,E1,E2,E3,O0,O1,O2,O3;
    dft4<SGN>(a[0],a[2],a[4],a[6], E0,E1,E2,E3);
    dft4<SGN>(a[1],a[3],a[5],a[7], O0,O1,O2,O3);
    float2 T1 = make_float2(C*(O1.x - (float)SGN*O1.y), C*((float)SGN*O1.x + O1.y));
    float2 T2 = make_float2((float)(-SGN)*O2.y, (float)SGN*O2.x);
    float2 T3 = make_float2(-C*(O3.x + (float)SGN*O3.y), C*((float)SGN*O3.x - O3.y));
    X[0]=cadd(E0,O0); X[4]=csub(E0,O0);
    X[1]=cadd(E1,T1); X[5]=csub(E1,T1);
    X[2]=cadd(E2,T2); X[6]=csub(E2,T2);
    X[3]=cadd(E3,T3); X[7]=csub(E3,T3);
}

template<int SGN>
__device__ __forceinline__ void dft16(const float2* v, float2* X) {
    const float ct[10] = {1.f, 0.92387953251f, 0.70710678119f, 0.38268343236f, 0.f,
                          0.f, -0.70710678119f, 0.f, 0.f, -0.92387953251f};
    const float st[10] = {0.f, 0.38268343236f, 0.70710678119f, 0.92387953251f, 1.f,
                          0.f, 0.70710678119f, 0.f, 0.f, -0.38268343236f};
    float2 Z[16];
    #pragma unroll
    for (int h0 = 0; h0 < 4; ++h0) {
        float2 y0,y1,y2,y3;
        dft4<SGN>(v[h0], v[4+h0], v[8+h0], v[12+h0], y0,y1,y2,y3);
        float2 ys[4] = {y0,y1,y2,y3};
        #pragma unroll
        for (int k0 = 0; k0 < 4; ++k0) {
            int m = h0 * k0;
            float cc = ct[m], ss = (float)SGN * st[m];
            Z[k0*4 + h0] = make_float2(ys[k0].x*cc - ys[k0].y*ss,
                                       ys[k0].x*ss + ys[k0].y*cc);
        }
    }
    #pragma unroll
    for (int k0 = 0; k0 < 4; ++k0) {
        float2 y0,y1,y2,y3;
        dft4<SGN>(Z[k0*4+0], Z[k0*4+1], Z[k0*4+2], Z[k0*4+3], y0,y1,y2,y3);
        X[k0] = y0; X[k0+4] = y1; X[k0+8] = y2; X[k0+12] = y3;
    }
}

// Z layout (uint4 = 4 half2 = 4 channels): index ((om*32 + cc)*16 + t)*64 + h.
// Each pmid block owns one contiguous 16 KB chunk (om,cc).

// ======== fused pass A: blocks 0..1023 = p1 (paired real W-FFT), 1024..1221 = k_prep ====
// p1 role: fp32 SoA LDS throughout; half2 conversion only at the global Z write.
__global__ __launch_bounds__(256) void pA(const float* __restrict__ x,
                                          uint4* __restrict__ Z,
                                          const float* __restrict__ Ak,
                                          const float* __restrict__ Bk,
                                          __half2* __restrict__ Ahw,
                                          __half2* __restrict__ Bhw) {
    __shared__ __align__(16) char smem[32768];
    int bid = blockIdx.x;
    int tid = threadIdx.x;
    if (bid < 1024) {
        float (*zsre)[64][32] = (float(*)[64][32])smem;             // 16 KB
        float (*zsim)[64][32] = (float(*)[64][32])(smem + 16384);   // 16 KB
        float (*spre)[64][32] = (float(*)[64][32])smem;             // alias
        float (*spim)[64][32] = (float(*)[64][32])(smem + 16384);   // alias
        int cq = bid & 3, hq = (bid >> 2) & 15, t = bid >> 6;
        int c = tid & 31, s4 = tid >> 5;           // s4 in [0,8)
        float twc[8], tws[8];
        {
            float s1, c1; sincosf(-PI2 * s4 / 64.0f, &s1, &c1);
            twc[0] = 1.f; tws[0] = 0.f;
            #pragma unroll
            for (int k = 1; k < 8; ++k) {
                twc[k] = twc[k-1]*c1 - tws[k-1]*s1;
                tws[k] = twc[k-1]*s1 + tws[k-1]*c1;
            }
        }
        const float* xb = x + (size_t)(t*64 + hq*4) * 8192 + cq * 32 + c;
        // stage 1: packed complex input (plane 2p = re, plane 2p+1 = im), fp32 out
        #pragma unroll
        for (int p = 0; p < 2; ++p) {
            float2 a[8], Y[8];
            #pragma unroll
            for (int h1 = 0; h1 < 8; ++h1) {
                size_t off = (size_t)(h1*8 + s4) * 128;
                a[h1] = make_float2(xb[(size_t)(2*p) * 8192 + off],
                                    xb[(size_t)(2*p+1) * 8192 + off]);
            }
            dft8<-1>(a, Y);
            #pragma unroll
            for (int k0 = 0; k0 < 8; ++k0) {
                int row = k0*8 + s4;
                zsre[p][row][c] = Y[k0].x*twc[k0] - Y[k0].y*tws[k0];
                zsim[p][row][c] = Y[k0].x*tws[k0] + Y[k0].y*twc[k0];
            }
        }
        __syncthreads();                                      // B1
        // stage 2: read ALL zs inputs for both pairs, dft8 in registers
        float2 X0[8], X1[8];
        {
            float2 b[8];
            #pragma unroll
            for (int h0 = 0; h0 < 8; ++h0)
                b[h0] = make_float2(zsre[0][s4*8 + h0][c], zsim[0][s4*8 + h0][c]);
            dft8<-1>(b, X0);
            #pragma unroll
            for (int h0 = 0; h0 < 8; ++h0)
                b[h0] = make_float2(zsre[1][s4*8 + h0][c], zsim[1][s4*8 + h0][c]);
            dft8<-1>(b, X1);
        }
        __syncthreads();                                      // B2 (all zs reads done -> alias safe)
        #pragma unroll
        for (int k1 = 0; k1 < 8; ++k1) {
            int row = s4 + 8*k1;
            spre[0][row][c] = X0[k1].x; spim[0][row][c] = X0[k1].y;
            spre[1][row][c] = X1[k1].x; spim[1][row][c] = X1[k1].y;
        }
        __syncthreads();                                      // B3
        // unpack + dense write: X1 = (Z(om)+conj(Z(mo)))/2, X2 = -i(Z(om)-conj)/2
        for (int i = tid; i < 528; i += 256) {                // p(2) x ccl(8) x om(33)
            int p = i & 1, ccl = (i >> 1) & 7, om = i >> 4;
            int mo = (64 - om) & 63;
            uint4 u1, u2;
            unsigned int* p1o = &u1.x;
            unsigned int* p2o = &u2.x;
            #pragma unroll
            for (int j = 0; j < 4; ++j) {
                int cb = ccl*4 + j;
                float2 za = make_float2(spre[p][om][cb], spim[p][om][cb]);
                float2 zb = make_float2(spre[p][mo][cb], spim[p][mo][cb]);
                float2 Xa = make_float2(0.5f*(za.x + zb.x), 0.5f*(za.y - zb.y));
                float2 Xb = make_float2(0.5f*(za.y + zb.y), 0.5f*(zb.x - za.x));
                __half2 h1v = __float22half2_rn(Xa);
                __half2 h2v = __float22half2_rn(Xb);
                p1o[j] = *(unsigned int*)&h1v;
                p2o[j] = *(unsigned int*)&h2v;
            }
            size_t base = ((size_t)(om*32 + cq*8 + ccl)*16 + t)*64 + hq*4;
            Z[base + 2*p]     = u1;
            Z[base + 2*p + 1] = u2;
        }
    } else {
        // ---------------- k_prep role (unchanged; exactly 32768 B) ----------------
        float (*Asl)[7][64] = (float(*)[7][64])smem;
        float (*Bsl)[7][64] = (float(*)[7][64])(smem + 12544);
        float2 (*Awl)[64]   = (float2(*)[64])(smem + 25088);
        float2 (*Bwl)[64]   = (float2(*)[64])(smem + 28672);
        float2* tw64        = (float2*)(smem + 32256);
        int kid = bid - 1024;
        int kt = kid / 66;
        int rem = kid % 66;
        int om = rem >> 1, chalf = rem & 1;
        int c0 = chalf * 64;
        for (int i = tid; i < 64; i += 256) {
            float s, cw; sincosf(-PI2 * i / 64.0f, &s, &cw);
            tw64[i] = make_float2(cw, s);
        }
        for (int i = tid; i < 49 * 64; i += 256) {
            int p = i >> 6, cl = i & 63;
            int kh = p / 7, kw = p % 7;
            int idx = (((c0 + cl) * 3 + kt) * 7 + kh) * 7 + kw;
            Asl[kh][kw][cl] = 0.9f * tanhf(Ak[idx]);
            Bsl[kh][kw][cl] = Bk[idx];
        }
        __syncthreads();
        for (int i = tid; i < 7 * 64; i += 256) {
            int kh = i >> 6, cl = i & 63;
            float2 aA = make_float2(0.f,0.f), aB = make_float2(0.f,0.f);
            #pragma unroll
            for (int kw = 0; kw < 7; ++kw) {
                float2 tw = tw64[(om * (kw - 3)) & 63];
                float va = Asl[kh][kw][cl], vb = Bsl[kh][kw][cl];
                aA.x = fmaf(va, tw.x, aA.x); aA.y = fmaf(va, tw.y, aA.y);
                aB.x = fmaf(vb, tw.x, aB.x); aB.y = fmaf(vb, tw.y, aB.y);
            }
            Awl[kh][cl] = aA; Bwl[kh][cl] = aB;
        }
        __syncthreads();
        for (int i = tid; i < 64 * 64; i += 256) {
            int eta = i >> 6, cl = i & 63;
            float2 aA = make_float2(0.f,0.f), aB = make_float2(0.f,0.f);
            #pragma unroll
            for (int kh = 0; kh < 7; ++kh) {
                float2 tw = tw64[(eta * (kh - 3)) & 63];
                aA = cmac(aA, Awl[kh][cl], tw);
                aB = cmac(aB, Bwl[kh][cl], tw);
            }
            int ep = ((eta & 7) << 3) | (eta >> 3);  // digit-swapped eta position
            int o = ((kt * 33 + om) * 64 + ep) * 128 + c0 + cl;
            Ahw[o] = __float22half2_rn(aA);
            Bhw[o] = __float22half2_rn(aB);
        }
    }
}

// ------- fused middle pass: fp32 SoA LDS (conversions only at global boundary) -------
__global__ __launch_bounds__(256) void pmid(uint4* __restrict__ Z,
                                            const __half2* __restrict__ Ahw,
                                            const __half2* __restrict__ Bhw) {
    __shared__ float tre[16][64][4];      // 16 KB
    __shared__ float tim[16][64][4];      // 16 KB
    int l = (blockIdx.x & 7) * 132 + (blockIdx.x >> 3);   // XCD-chunked, bijective
    int om = l >> 5, cc = l & 31;
    int c0 = cc * 4;
    int tid = threadIdx.x;
    uint4* g = Z + (size_t)l * 1024;

    int d = tid & 7;
    float twc[8], tws[8];
    {
        float s1, c1; sincosf(-PI2 * d / 64.0f, &s1, &c1);
        twc[0] = 1.f; tws[0] = 0.f;
        #pragma unroll
        for (int k = 1; k < 8; ++k) {
            twc[k] = twc[k-1]*c1 - tws[k-1]*s1;
            tws[k] = twc[k-1]*s1 + tws[k-1]*c1;
        }
    }
    // load: contiguous 16 KB; convert half->float ONCE
    for (int i = tid; i < 1024; i += 256) {
        uint4 u = g[i];
        int t = i >> 6, h = i & 63;
        int pr = LROW(h);
        float2 v0 = __half22float2(*(__half2*)&u.x);
        float2 v1 = __half22float2(*(__half2*)&u.y);
        float2 v2 = __half22float2(*(__half2*)&u.z);
        float2 v3 = __half22float2(*(__half2*)&u.w);
        tre[t][pr][0] = v0.x; tim[t][pr][0] = v0.y;
        tre[t][pr][1] = v1.x; tim[t][pr][1] = v1.y;
        tre[t][pr][2] = v2.x; tim[t][pr][2] = v2.y;
        tre[t][pr][3] = v3.x; tim[t][pr][3] = v3.y;
    }
    __syncthreads();
    int cl = (tid >> 3) & 3, ts = tid >> 5;          // ts in [0,8)
    // H forward stage 1
    #pragma unroll
    for (int q = 0; q < 2; ++q) {
        int t = ts*2 + q;
        float2 a[8], Y[8];
        #pragma unroll
        for (int h1 = 0; h1 < 8; ++h1) {
            int pr = LROW(h1*8 + d);
            a[h1] = make_float2(tre[t][pr][cl], tim[t][pr][cl]);
        }
        dft8<-1>(a, Y);
        #pragma unroll
        for (int k0 = 0; k0 < 8; ++k0) {
            int pr = LROW(k0*8 + d);
            tre[t][pr][cl] = Y[k0].x*twc[k0] - Y[k0].y*tws[k0];
            tim[t][pr][cl] = Y[k0].x*tws[k0] + Y[k0].y*twc[k0];
        }
    }
    __syncthreads();
    // H forward stage 2
    #pragma unroll
    for (int q = 0; q < 2; ++q) {
        int t = ts*2 + q;
        float2 a[8], Y[8];
        #pragma unroll
        for (int h0 = 0; h0 < 8; ++h0) {
            int pr = LROW(d*8 + h0);
            a[h0] = make_float2(tre[t][pr][cl], tim[t][pr][cl]);
        }
        dft8<-1>(a, Y);
        #pragma unroll
        for (int k1 = 0; k1 < 8; ++k1) {
            int pr = LROW(d*8 + k1);
            tre[t][pr][cl] = Y[k1].x; tim[t][pr][cl] = Y[k1].y;
        }
    }
    __syncthreads();
    // T phase
    {
        const float CT16[16] = {1.f, 0.9238795325f, 0.7071067812f, 0.3826834324f, 0.f,
                                -0.3826834324f, -0.7071067812f, -0.9238795325f, -1.f,
                                -0.9238795325f, -0.7071067812f, -0.3826834324f, 0.f,
                                0.3826834324f, 0.7071067812f, 0.9238795325f};
        const float ST16[16] = {0.f, 0.3826834324f, 0.7071067812f, 0.9238795325f, 1.f,
                                0.9238795325f, 0.7071067812f, 0.3826834324f, 0.f,
                                -0.3826834324f, -0.7071067812f, -0.9238795325f, -1.f,
                                -0.9238795325f, -0.7071067812f, -0.3826834324f};
        int cg = tid & 3, rT = tid >> 2;             // rT in [0,64)
        const int PKT = 33 * 64 * 128;
        int kb = (om * 64 + rT) * 128 + c0 + cg;
        float2 A0 = __half22float2(Ahw[kb]);
        float2 A1 = __half22float2(Ahw[kb + PKT]);
        float2 A2 = __half22float2(Ahw[kb + 2*PKT]);
        float2 B0 = __half22float2(Bhw[kb]);
        float2 B1 = __half22float2(Bhw[kb + PKT]);
        float2 B2 = __half22float2(Bhw[kb + 2*PKT]);
        int pr = LROW(rT);
        float2 v[16], X[16];
        #pragma unroll
        for (int t = 0; t < 16; ++t) v[t] = make_float2(tre[t][pr][cg], tim[t][pr][cg]);
        dft16<-1>(v, X);
        #pragma unroll
        for (int ta = 0; ta < 16; ++ta) {
            float2 wv = make_float2(CT16[ta], -ST16[ta]);
            float2 wc = make_float2(CT16[ta],  ST16[ta]);
            float2 Af = A1; Af = cmac(Af, A0, wc); Af = cmac(Af, A2, wv);
            float2 Bf = B1; Bf = cmac(Bf, B0, wc); Bf = cmac(Bf, B2, wv);
            float2 A2q = csq(Af), A4q = csq(A2q);
            float2 S = cmul(make_float2(1.f+Af.x, Af.y), make_float2(1.f+A2q.x, A2q.y));
            S = cmul(S, make_float2(1.f+A4q.x, A4q.y));
            float2 G = cmul(S, Bf);
            X[ta] = cmul(X[ta], G);
        }
        dft16<1>(X, v);
        const float sc = 0.015625f;                  // 1/64 fold
        #pragma unroll
        for (int t = 0; t < 16; ++t) {
            tre[t][pr][cg] = v[t].x * sc;
            tim[t][pr][cg] = v[t].y * sc;
        }
    }
    __syncthreads();
    // inverse H stage 1
    #pragma unroll
    for (int q = 0; q < 2; ++q) {
        int t = ts*2 + q;
        float2 a[8], Y[8];
        #pragma unroll
        for (int e1 = 0; e1 < 8; ++e1) {
            int pr = LROW(d*8 + e1);
            a[e1] = make_float2(tre[t][pr][cl], tim[t][pr][cl]);
        }
        dft8<1>(a, Y);
        #pragma unroll
        for (int h0 = 0; h0 < 8; ++h0) {
            int pr = LROW(d*8 + h0);
            tre[t][pr][cl] =  Y[h0].x*twc[h0] + Y[h0].y*tws[h0];
            tim[t][pr][cl] = -Y[h0].x*tws[h0] + Y[h0].y*twc[h0];
        }
    }
    __syncthreads();
    // inverse H stage 2
    #pragma unroll
    for (int q = 0; q < 2; ++q) {
        int t = ts*2 + q;
        float2 a[8], Y[8];
        #pragma unroll
        for (int e0 = 0; e0 < 8; ++e0) {
            int pr = LROW(e0*8 + d);
            a[e0] = make_float2(tre[t][pr][cl], tim[t][pr][cl]);
        }
        dft8<1>(a, Y);
        #pragma unroll
        for (int h1 = 0; h1 < 8; ++h1) {
            int pr = LROW(d + 8*h1);
            tre[t][pr][cl] = Y[h1].x; tim[t][pr][cl] = Y[h1].y;
        }
    }
    __syncthreads();
    // write back: convert float->half ONCE
    for (int i = tid; i < 1024; i += 256) {
        int t = i >> 6, h = i & 63;
        int pr = LROW(h);
        uint4 u;
        __half2 v0 = __float22half2_rn(make_float2(tre[t][pr][0], tim[t][pr][0]));
        __half2 v1 = __float22half2_rn(make_float2(tre[t][pr][1], tim[t][pr][1]));
        __half2 v2 = __float22half2_rn(make_float2(tre[t][pr][2], tim[t][pr][2]));
        __half2 v3 = __float22half2_rn(make_float2(tre[t][pr][3], tim[t][pr][3]));
        u.x = *(unsigned int*)&v0; u.y = *(unsigned int*)&v1;
        u.z = *(unsigned int*)&v2; u.w = *(unsigned int*)&v3;
        g[i] = u;
    }
}

// ------- pass 5: paired inverse real-output W-FFT, fp32 SoA LDS -------
__global__ __launch_bounds__(256) void p5(const uint4* __restrict__ Z,
                                          float* __restrict__ out) {
    __shared__ float plre[2][64][32];      // 16 KB
    __shared__ float plim[2][64][32];      // 16 KB
    __shared__ float2 tw64[64];
    int bid = blockIdx.x;
    int cq = bid & 3, hq = (bid >> 2) & 15, t = bid >> 6;
    int tid = threadIdx.x;
    if (tid < 64) {
        float s, cw; sincosf(PI2 * tid / 64.0f, &s, &cw);
        tw64[tid] = make_float2(cw, s);
    }
    // phase 1: read both planes of each pair, pack + Hermitian mirror (fp32 in LDS)
    for (int i = tid; i < 528; i += 256) {               // p(2) x ccl(8) x om(33)
        int p = i & 1, ccl = (i >> 1) & 7, om = i >> 4;
        size_t base = ((size_t)(om*32 + cq*8 + ccl)*16 + t)*64 + hq*4;
        uint4 ua = Z[base + 2*p];
        uint4 ub = Z[base + 2*p + 1];
        const unsigned int* pa = &ua.x;
        const unsigned int* pb = &ub.x;
        #pragma unroll
        for (int j = 0; j < 4; ++j) {
            float2 za = __half22float2(*(const __half2*)&pa[j]);
            float2 zb = __half22float2(*(const __half2*)&pb[j]);
            plre[p][om][ccl*4+j] = za.x - zb.y;
            plim[p][om][ccl*4+j] = za.y + zb.x;
            if (om >= 1 && om <= 31) {
                plre[p][64-om][ccl*4+j] = za.x + zb.y;
                plim[p][64-om][ccl*4+j] = zb.x - za.y;
            }
        }
    }
    __syncthreads();                                          // B1
    int c = tid & 31, s4 = tid >> 5;
    float2 ar[2][8];
    #pragma unroll
    for (int p = 0; p < 2; ++p)
        #pragma unroll
        for (int h1 = 0; h1 < 8; ++h1)
            ar[p][h1] = make_float2(plre[p][h1*8 + s4][c], plim[p][h1*8 + s4][c]);
    __syncthreads();                                          // B2
    #pragma unroll
    for (int p = 0; p < 2; ++p) {
        float2 Y[8];
        dft8<1>(ar[p], Y);
        #pragma unroll
        for (int k0 = 0; k0 < 8; ++k0) {
            float2 z = cmul(Y[k0], tw64[(s4 * k0) & 63]);
            plre[p][k0*8 + s4][c] = z.x;
            plim[p][k0*8 + s4][c] = z.y;
        }
    }
    __syncthreads();                                          // B3
    #pragma unroll
    for (int p = 0; p < 2; ++p) {
        float2 b[8], X[8];
        #pragma unroll
        for (int h0 = 0; h0 < 8; ++h0)
            b[h0] = make_float2(plre[p][s4*8 + h0][c], plim[p][s4*8 + h0][c]);
        dft8<1>(b, X);
        float* dst = out + (size_t)(t*64 + hq*4 + 2*p) * 8192 + cq * 32 + c;
        #pragma unroll
        for (int k1 = 0; k1 < 8; ++k1) {
            size_t o = (size_t)(s4 + 8*k1) * 128;
            dst[o]        = X[k1].x * (1.0f / 1024.0f);
            dst[o + 8192] = X[k1].y * (1.0f / 1024.0f);
        }
    }
}

extern "C" void kernel_launch(void* const* d_in, const int* in_sizes, int n_in,
                              void* d_out, int out_size, void* d_ws, size_t ws_size,
                              hipStream_t stream) {
    const float* x  = (const float*)d_in[0];
    const float* Ak = (const float*)d_in[1];
    const float* Bk = (const float*)d_in[2];
    float* out = (float*)d_out;

    // Z: 33*32 chunks x 16 KB = 17.3 MB (uint4-addressed); G tables after.
    uint4* Z = (uint4*)d_ws;
    __half2* Ahw = (__half2*)((char*)d_ws + (size_t)33*32*1024*16);
    __half2* Bhw = Ahw + 3 * 33 * 64 * 128;

    hipLaunchKernelGGL(pA,   dim3(1222), dim3(256), 0, stream, x, Z, Ak, Bk, Ahw, Bhw);
    hipLaunchKernelGGL(pmid, dim3(1056), dim3(256), 0, stream, Z, Ahw, Bhw);
    hipLaunchKernelGGL(p5,   dim3(1024), dim3(256), 0, stream, Z, out);
}